// Round 3
// baseline (2074.124 us; speedup 1.0000x reference)
//
#include <hip/hip_runtime.h>
#include <hip/hip_bf16.h>

// ---------------------------------------------------------------------------
// BiLSTMDecoderModel: V=100000 E=300 H=512 NCLS=6 B=128 S=256
//  * backward LSTM contributes only b_hs[0] = ONE step on seq_emb[0] (h0=0,
//    b_Whh unused).
//  * decoder input projection gi[c] is batch-invariant -> precompute [6][3072].
//  * forward LSTM: persistent kernel, 8 groups x 32 WGs, weights pinned in
//    VGPR/AGPR, XCD-localized groups (g = bid&7), flag-based barrier with
//    ZERO atomic RMWs (round-2 lesson: 32 serialized fetch_adds on one hot
//    line = 6.3us/step), x/h as direct register fragments (no LDS staging).
// ---------------------------------------------------------------------------

typedef unsigned short ush;
typedef unsigned long long u64;
typedef __bf16 bf16x8 __attribute__((ext_vector_type(8)));
typedef float  f32x4  __attribute__((ext_vector_type(4)));
typedef unsigned short us8 __attribute__((ext_vector_type(8)));
typedef unsigned long long u64x2 __attribute__((ext_vector_type(2)));

__device__ __forceinline__ ush f2b(float f) {
    __hip_bfloat16 h = __float2bfloat16(f);
    return __builtin_bit_cast(ush, h);
}
__device__ __forceinline__ float b2f(ush u) {
    return __bfloat162float(__builtin_bit_cast(__hip_bfloat16, u));
}
__device__ __forceinline__ float sigm(float x) { return 1.0f / (1.0f + expf(-x)); }

__device__ __forceinline__ bf16x8 ldf(const ush* p) {
    return __builtin_bit_cast(bf16x8, *(const us8*)p);
}
__device__ __forceinline__ f32x4 mfma16(bf16x8 a, bf16x8 b, f32x4 c) {
    // D[m][n] += sum_k A[m][k]*B[k][n]; A: m=lane&15,k=(lane>>4)*8+j
    // B: n=lane&15,k=(lane>>4)*8+j; D: n=lane&15, m=(lane>>4)*4+reg
    return __builtin_amdgcn_mfma_f32_16x16x32_bf16(a, b, c, 0, 0, 0);
}

// ---- sizes / ws layout (bytes) --------------------------------------------
#define NB   128
#define NS   256
#define NE   300
#define EPL  328          // seq_emb row stride (ush); 328*2=656B, 16B-aligned
#define NH   512
#define HPL  520
#define DH   1024
#define DHL  1032

static const size_t OFF_SEQ  = 0;              // seq_emb [256][128][328] ush = 21,495,808
static const size_t OFF_WIH  = 21495808;       // Wih_r   [2048][328] ush    = 1,343,488
static const size_t OFF_WHH  = 22839296;       // Whh_r   [2048][520] ush    = 2,129,920
static const size_t OFF_BWT  = 24969216;       // bWihT   [320][2048] ush    = 1,310,720
static const size_t OFF_DWHH = 26279936;       // dWhh_r  [3072][1032] ush   = 6,340,608
static const size_t OFF_GI   = 32620544;       // gi      [6][3072] f32      = 73,728
static const size_t OFF_HR   = 32694272;       // h ring  [2][128][512] ush  = 262,144
static const size_t OFF_FLAG = 32956416;       // flags   [256][8][32] u32   = 262,144
static const size_t OFF_BG   = 33218560;       // bgates  [128][2048] f32    = 1,048,576
static const size_t OFF_HDEC = 34267136;       // h_dec   [2][128][1024] ush = 524,288
// total = 34,791,424 bytes (~33.2 MiB)

// ---- embedding gather + tanh -> bf16, row stride EPL (zero pad) ------------
__global__ __launch_bounds__(64) void embed_k(const int* __restrict__ seq,
                                              const float* __restrict__ embW,
                                              ush* __restrict__ seq_emb) {
    int t = blockIdx.x & 255, b = blockIdx.x >> 8;
    int tok = seq[b * NS + t];
    const float* src = embW + (size_t)tok * NE;
    ush* dst = seq_emb + ((size_t)t * NB + b) * EPL;
    for (int e = threadIdx.x; e < EPL; e += 64)
        dst[e] = (e < NE) ? f2b(tanhf(src[e])) : (ush)0;
}

// ---- weight conversions ----------------------------------------------------
__global__ __launch_bounds__(128) void conv_wih(const float* __restrict__ W, ush* __restrict__ out) {
    int R = blockIdx.x, w = R >> 6, v = (R >> 4) & 3, jl = R & 15;
    int src = v * NH + w * 16 + jl;
    for (int k = threadIdx.x; k < EPL; k += 128)
        out[(size_t)R * EPL + k] = (k < NE) ? f2b(W[(size_t)src * NE + k]) : (ush)0;
}
__global__ __launch_bounds__(128) void conv_whh(const float* __restrict__ W, ush* __restrict__ out) {
    int R = blockIdx.x, w = R >> 6, v = (R >> 4) & 3, jl = R & 15;
    int src = v * NH + w * 16 + jl;
    for (int k = threadIdx.x; k < HPL; k += 128)
        out[(size_t)R * HPL + k] = (k < NH) ? f2b(W[(size_t)src * NH + k]) : (ush)0;
}
__global__ __launch_bounds__(256) void conv_bwihT(const float* __restrict__ W, ush* __restrict__ out) {
    int k = blockIdx.x;
    for (int r = threadIdx.x; r < 2048; r += 256)
        out[(size_t)k * 2048 + r] = (k < NE) ? f2b(W[(size_t)r * NE + k]) : (ush)0;
}
__global__ __launch_bounds__(128) void conv_dwhh(const float* __restrict__ W, ush* __restrict__ out) {
    int R = blockIdx.x;
    for (int k = threadIdx.x; k < DHL; k += 128)
        out[(size_t)R * DHL + k] = (k < DH) ? f2b(W[(size_t)R * DH + k]) : (ush)0;
}

// ---- decoder class-input projection ----------------------------------------
__global__ __launch_bounds__(256) void gi_k(const int* __restrict__ classes,
                                            const float* __restrict__ ecW,
                                            const float* __restrict__ dWih,
                                            const float* __restrict__ dbih,
                                            float* __restrict__ gi) {
    __shared__ float ce[NH];
    int c = blockIdx.x / 12, chunk = blockIdx.x % 12;
    int cls = classes[c];
    for (int i = threadIdx.x; i < NH; i += 256) ce[i] = tanhf(ecW[(size_t)cls * NH + i]);
    __syncthreads();
    int r = chunk * 256 + threadIdx.x;
    float acc = dbih[r];
    for (int k = 0; k < NH; ++k) acc += dWih[(size_t)r * NH + k] * ce[k];
    gi[c * 3072 + r] = acc;
}

// ---- backward-LSTM single step (h0 second half) ----------------------------
__global__ __launch_bounds__(256) void bgate_k(const ush* __restrict__ seq_emb,
                                               const ush* __restrict__ bWihT,
                                               const float* __restrict__ bb,
                                               float* __restrict__ bg) {
    int b = blockIdx.y, r = blockIdx.x * 256 + threadIdx.x;
    const ush* x0 = seq_emb + (size_t)b * EPL;
    float acc = bb[r];
    for (int k = 0; k < NE; ++k) acc += b2f(x0[k]) * b2f(bWihT[(size_t)k * 2048 + r]);
    bg[(size_t)b * 2048 + r] = acc;
}
__global__ __launch_bounds__(256) void bpoint_k(const float* __restrict__ bg,
                                                ush* __restrict__ h_dec0) {
    int idx = blockIdx.x * 256 + threadIdx.x;
    int b = idx >> 9, j = idx & 511;
    const float* g = bg + (size_t)b * 2048;
    float c_ = sigm(g[j]) * tanhf(g[1024 + j]);
    float h_ = sigm(g[1536 + j]) * tanhf(c_);
    h_dec0[(size_t)b * DH + NH + j] = f2b(h_);
}

// ---- persistent forward LSTM (flag barrier, no RMW) ------------------------
// grid 256: group g = bid&7 (16 batch rows, XCD-local), WG w = bid>>3
// (h-dims w*16..+16). 4 waves = 4 gates. Weights in VGPR/AGPR.
// Per step: x frags prefetched 1 iter ahead (plain cached, L2-local);
// h frags read as relaxed agent u64 loads (UC, MALL-coherent);
// publish = UC pair stores -> vmcnt(0) -> barrier -> one UC flag store;
// wait = 32 parallel flag loads + __all (one round trip, no RMWs).
__global__ __launch_bounds__(256, 1) void lstm_pers(const ush* __restrict__ seq_emb,
                                                    const ush* __restrict__ Wih_r,
                                                    const ush* __restrict__ Whh_r,
                                                    const float* __restrict__ fb,
                                                    ush* __restrict__ h_ring,
                                                    ush* __restrict__ h_dec0,
                                                    unsigned* __restrict__ flags) {
    __shared__ float gates[16 * 66];   // [m][gate*16+jl], stride 66: <=2-way banks

    const int tid = threadIdx.x;
    const int lane = tid & 63, v = tid >> 6;
    const int l15 = lane & 15, l4 = lane >> 4;
    const int g = blockIdx.x & 7, w = blockIdx.x >> 3;
    const int bl = tid >> 4, jl = tid & 15;

    // one-time: weight fragments into registers, pinned with opaque asm
    bf16x8 wf[10], hf[16];
    {
        const ush* wp = Wih_r + (size_t)((w * 4 + v) * 16 + l15) * EPL + l4 * 8;
#pragma unroll
        for (int ks = 0; ks < 10; ++ks) wf[ks] = ldf(wp + ks * 32);
        const ush* hp = Whh_r + (size_t)((w * 4 + v) * 16 + l15) * HPL + l4 * 8;
#pragma unroll
        for (int ks = 0; ks < 16; ++ks) hf[ks] = ldf(hp + ks * 32);
    }
#pragma unroll
    for (int ks = 0; ks < 10; ++ks) {
        f32x4 tmp = __builtin_bit_cast(f32x4, wf[ks]);
        asm volatile("" : "+v"(tmp));
        wf[ks] = __builtin_bit_cast(bf16x8, tmp);
    }
#pragma unroll
    for (int ks = 0; ks < 16; ++ks) {
        f32x4 tmp = __builtin_bit_cast(f32x4, hf[ks]);
        asm volatile("" : "+v"(tmp));
        hf[ks] = __builtin_bit_cast(bf16x8, tmp);
    }

    const float bias = fb[v * NH + w * 16 + l15];
    float c_reg = 0.0f;

    // prologue: x[0] fragments -> xacc
    us8 xfn[10];
    f32x4 xacc = {bias, bias, bias, bias};
    {
        const ush* xs = seq_emb + (size_t)(g * 16 + l15) * EPL + l4 * 8;
#pragma unroll
        for (int ks = 0; ks < 10; ++ks) xfn[ks] = *(const us8*)(xs + ks * 32);
#pragma unroll
        for (int ks = 0; ks < 10; ++ks)
            xacc = mfma16(__builtin_bit_cast(bf16x8, xfn[ks]), wf[ks], xacc);
    }

    for (int t = 0; t < NS; ++t) {
        // issue x[t+1] fragment loads early (consumed at bottom; hides HBM/L2)
        if (t + 1 < NS) {
            const ush* xs = seq_emb + ((size_t)(t + 1) * NB + g * 16 + l15) * EPL + l4 * 8;
#pragma unroll
            for (int ks = 0; ks < 10; ++ks) xfn[ks] = *(const us8*)(xs + ks * 32);
        }

        // gates = xacc + h @ WhhT  (h frags direct from MALL, UC)
        f32x4 acc = xacc;
        if (t > 0) {
            const ush* hp = h_ring + ((size_t)(t & 1) * NB + g * 16 + l15) * NH + l4 * 8;
            bf16x8 hfr[16];
#pragma unroll
            for (int ks = 0; ks < 16; ++ks) {
                u64x2 tv;
                tv.x = __hip_atomic_load((const u64*)(hp + ks * 32),
                                         __ATOMIC_RELAXED, __HIP_MEMORY_SCOPE_AGENT);
                tv.y = __hip_atomic_load((const u64*)(hp + ks * 32) + 1,
                                         __ATOMIC_RELAXED, __HIP_MEMORY_SCOPE_AGENT);
                hfr[ks] = __builtin_bit_cast(bf16x8, tv);
            }
#pragma unroll
            for (int ks = 0; ks < 16; ++ks)
                acc = mfma16(hfr[ks], hf[ks], acc);
        }
#pragma unroll
        for (int r0 = 0; r0 < 4; ++r0)
            gates[(l4 * 4 + r0) * 66 + v * 16 + l15] = acc[r0];
        __syncthreads();                                  // sync1

        // gating (per-thread c stays in a register)
        float gi_ = gates[bl * 66 + jl];
        float gf_ = gates[bl * 66 + 16 + jl];
        float gg_ = gates[bl * 66 + 32 + jl];
        float go_ = gates[bl * 66 + 48 + jl];
        float c_ = sigm(gf_) * c_reg + sigm(gi_) * tanhf(gg_);
        float h_ = sigm(go_) * tanhf(c_);
        c_reg = c_;
        ush hb = f2b(h_);

        if (t == NS - 1) {
            h_dec0[(size_t)(g * 16 + bl) * DH + w * 16 + jl] = hb;
            break;                                        // uniform
        }

        // publish h slice: UC dword stores (pairs), no fences, no RMWs
        unsigned nb = (unsigned)__shfl_down((int)hb, 1, 64);
        if ((jl & 1) == 0) {
            unsigned pair = (unsigned)hb | (nb << 16);
            unsigned* dst = (unsigned*)&h_ring[((size_t)((t + 1) & 1) * NB + g * 16 + bl) * NH + w * 16 + jl];
            __hip_atomic_store(dst, pair, __ATOMIC_RELAXED, __HIP_MEMORY_SCOPE_AGENT);
        }
        asm volatile("s_waitcnt vmcnt(0)" ::: "memory");  // h acked at MALL
        __syncthreads();                                  // sync2: all waves acked
        if (tid == 0)
            __hip_atomic_store(&flags[((size_t)(t + 1) * 8 + g) * 32 + w], 1u,
                               __ATOMIC_RELAXED, __HIP_MEMORY_SCOPE_AGENT);

        // xacc for t+1 (overlaps flag propagation)
        f32x4 nx = {bias, bias, bias, bias};
#pragma unroll
        for (int ks = 0; ks < 10; ++ks)
            nx = mfma16(__builtin_bit_cast(bf16x8, xfn[ks]), wf[ks], nx);
        xacc = nx;

        // wait: 32 parallel flag loads, one round trip per poll
        {
            const unsigned* fl = flags + ((size_t)(t + 1) * 8 + g) * 32;
            bool done;
            do {
                unsigned f = (lane < 32)
                    ? __hip_atomic_load(fl + lane, __ATOMIC_RELAXED, __HIP_MEMORY_SCOPE_AGENT)
                    : 1u;
                done = __all(f != 0);
            } while (!done);
        }
    }
}

// ---- decoder GRU step ------------------------------------------------------
__global__ __launch_bounds__(256) void gru_step(const ush* __restrict__ h_in,
                                                ush* __restrict__ h_out,
                                                const ush* __restrict__ dWhh_r,
                                                const float* __restrict__ gi,
                                                const float* __restrict__ dbhh) {
    __shared__ ush h_lds[16 * DHL];
    const int tid = threadIdx.x, lane = tid & 63, v = tid >> 6;
    const int l15 = lane & 15, l4 = lane >> 4;
    const int bB = blockIdx.x * 16, jB = blockIdx.y * 64;

    for (int i = tid; i < 2048; i += 256) {
        int r = i >> 7, c = i & 127;
        *(us8*)&h_lds[r * DHL + c * 8] = *(const us8*)&h_in[(size_t)(bB + r) * DH + c * 8];
    }
    __syncthreads();

    const int jg = jB + v * 16 + l15;
    float b0 = dbhh[jg], b1 = dbhh[DH + jg], b2 = dbhh[2 * DH + jg];
    f32x4 aR = {b0, b0, b0, b0}, aZ = {b1, b1, b1, b1}, aN = {b2, b2, b2, b2};
    const ush* pR = dWhh_r + (size_t)(0 * DH + jg) * DHL + l4 * 8;
    const ush* pZ = dWhh_r + (size_t)(1 * DH + jg) * DHL + l4 * 8;
    const ush* pN = dWhh_r + (size_t)(2 * DH + jg) * DHL + l4 * 8;
#pragma unroll
    for (int ks = 0; ks < 32; ++ks) {
        bf16x8 a = ldf(&h_lds[l15 * DHL + ks * 32 + l4 * 8]);
        aR = mfma16(a, ldf(pR + ks * 32), aR);
        aZ = mfma16(a, ldf(pZ + ks * 32), aZ);
        aN = mfma16(a, ldf(pN + ks * 32), aN);
    }
    const float giR = gi[jg], giZ = gi[DH + jg], giN = gi[2 * DH + jg];
#pragma unroll
    for (int r0 = 0; r0 < 4; ++r0) {
        int m = l4 * 4 + r0;
        float r_ = sigm(giR + aR[r0]);
        float z_ = sigm(giZ + aZ[r0]);
        float n_ = tanhf(giN + r_ * aN[r0]);
        float hold = b2f(h_lds[m * DHL + jg]);
        float ho = tanhf((1.0f - z_) * n_ + z_ * hold);
        h_out[(size_t)(bB + m) * DH + jg] = f2b(ho);
    }
}

// ---- logits + log_softmax(2) ----------------------------------------------
__global__ __launch_bounds__(64) void logits_k(const ush* __restrict__ h,
                                               const float* __restrict__ clsW,
                                               const float* __restrict__ clsb,
                                               float* __restrict__ out) {
    int b = blockIdx.x, lane = threadIdx.x;
    float s0 = 0.f, s1 = 0.f;
    for (int k = lane; k < DH; k += 64) {
        float hv = b2f(h[(size_t)b * DH + k]);
        s0 += hv * clsW[k];
        s1 += hv * clsW[DH + k];
    }
    for (int off = 32; off; off >>= 1) {
        s0 += __shfl_down(s0, off, 64);
        s1 += __shfl_down(s1, off, 64);
    }
    if (lane == 0) {
        float l0 = s0 + clsb[0], l1 = s1 + clsb[1];
        float m = fmaxf(l0, l1);
        float d = logf(expf(l0 - m) + expf(l1 - m));
        out[b * 2 + 0] = l0 - m - d;
        out[b * 2 + 1] = l1 - m - d;
    }
}

// ---------------------------------------------------------------------------
extern "C" void kernel_launch(void* const* d_in, const int* in_sizes, int n_in,
                              void* d_out, int out_size, void* d_ws, size_t ws_size,
                              hipStream_t stream) {
    (void)in_sizes; (void)n_in; (void)out_size; (void)ws_size;
    const int*   seq  = (const int*)  d_in[0];
    const int*   cls  = (const int*)  d_in[1];
    const float* embW = (const float*)d_in[2];
    const float* ecW  = (const float*)d_in[3];
    const float* fWih = (const float*)d_in[4];
    const float* fWhh = (const float*)d_in[5];
    const float* fb   = (const float*)d_in[6];
    const float* bWih = (const float*)d_in[7];
    /* d_in[8] = b_Whh unused (h0 = 0) */
    const float* bb   = (const float*)d_in[9];
    const float* dWih = (const float*)d_in[10];
    const float* dWhh = (const float*)d_in[11];
    const float* dbih = (const float*)d_in[12];
    const float* dbhh = (const float*)d_in[13];
    const float* clsW = (const float*)d_in[14];
    const float* clsb = (const float*)d_in[15];
    float* outF = (float*)d_out;

    char* ws = (char*)d_ws;
    ush*      seq_emb = (ush*)(ws + OFF_SEQ);
    ush*      Wih_r   = (ush*)(ws + OFF_WIH);
    ush*      Whh_r   = (ush*)(ws + OFF_WHH);
    ush*      bWihT   = (ush*)(ws + OFF_BWT);
    ush*      dWhh_r  = (ush*)(ws + OFF_DWHH);
    float*    gi      = (float*)(ws + OFF_GI);
    ush*      h_ring  = (ush*)(ws + OFF_HR);
    unsigned* flags   = (unsigned*)(ws + OFF_FLAG);
    float*    bg      = (float*)(ws + OFF_BG);
    ush*      h_dec   = (ush*)(ws + OFF_HDEC);

    // zero barrier flags (graph replays this each run; h_ring needs no init)
    hipMemsetAsync(ws + OFF_FLAG, 0, 262144, stream);

    embed_k<<<NB * NS, 64, 0, stream>>>(seq, embW, seq_emb);
    conv_wih<<<2048, 128, 0, stream>>>(fWih, Wih_r);
    conv_whh<<<2048, 128, 0, stream>>>(fWhh, Whh_r);
    conv_bwihT<<<320, 256, 0, stream>>>(bWih, bWihT);
    conv_dwhh<<<3072, 128, 0, stream>>>(dWhh, dWhh_r);
    gi_k<<<72, 256, 0, stream>>>(cls, ecW, dWih, dbih, gi);
    bgate_k<<<dim3(8, NB), 256, 0, stream>>>(seq_emb, bWihT, bb, bg);
    bpoint_k<<<256, 256, 0, stream>>>(bg, h_dec);

    lstm_pers<<<256, 256, 0, stream>>>(seq_emb, Wih_r, Whh_r, fb, h_ring, h_dec, flags);

    for (int c = 0; c < 6; ++c) {
        const ush* hin = h_dec + (size_t)(c & 1) * NB * DH;
        ush* hout      = h_dec + (size_t)((c + 1) & 1) * NB * DH;
        gru_step<<<dim3(8, 16), 256, 0, stream>>>(hin, hout, dWhh_r, gi + c * 3072, dbhh);
        logits_k<<<NB, 64, 0, stream>>>(hout, clsW, clsb, outF + c * NB * 2);
    }
}

// Round 4
// 1353.310 us; speedup vs baseline: 1.5326x; 1.5326x over previous
//
#include <hip/hip_runtime.h>
#include <hip/hip_bf16.h>

// ---------------------------------------------------------------------------
// BiLSTMDecoderModel: V=100000 E=300 H=512 NCLS=6 B=128 S=256
//  * backward LSTM = b_hs[0] only = ONE step on x[0] (h0=0, b_Whh unused).
//  * decoder input projection gi[c] batch-invariant -> precompute [6][3072].
//  * forward LSTM restructured (round-4):
//      - x@WihT hoisted into a parallel GEMM -> gx[256][128][2048] bf16
//      - scan: 8 groups x 8 WGs x 1024 thr (16 waves), 64 dims/WG,
//        Whh frags in VGPR (64/wave), group-h staged once/WG via LDS,
//        fence-free flag barrier, fan-in 8.
//    Round-2/3 lesson: both barrier styles hit ~6.5us/step; common cost was
//    128x MALL read amplification (2MB/group/step) + fan-in 32. This cuts
//    MALL volume 16x and fan-in 4x.
// ---------------------------------------------------------------------------

typedef unsigned short ush;
typedef unsigned long long u64;
typedef __bf16 bf16x8 __attribute__((ext_vector_type(8)));
typedef float  f32x4  __attribute__((ext_vector_type(4)));
typedef unsigned short us8 __attribute__((ext_vector_type(8)));

__device__ __forceinline__ ush f2b(float f) {
    __hip_bfloat16 h = __float2bfloat16(f);
    return __builtin_bit_cast(ush, h);
}
__device__ __forceinline__ float b2f(ush u) {
    return __bfloat162float(__builtin_bit_cast(__hip_bfloat16, u));
}
__device__ __forceinline__ float sigm(float x) { return 1.0f / (1.0f + expf(-x)); }
__device__ __forceinline__ bf16x8 ldf(const ush* p) {
    return __builtin_bit_cast(bf16x8, *(const us8*)p);
}
__device__ __forceinline__ f32x4 mfma16(bf16x8 a, bf16x8 b, f32x4 c) {
    // D[m][n] += sum_k A[m][k]*B[k][n]; A: m=lane&15,k=(lane>>4)*8+j
    // B: n=lane&15,k=(lane>>4)*8+j; D: n=lane&15, m=(lane>>4)*4+reg
    return __builtin_amdgcn_mfma_f32_16x16x32_bf16(a, b, c, 0, 0, 0);
}

// ---- sizes / ws layout (bytes) --------------------------------------------
#define NB   128
#define NS   256
#define NE   300
#define XL   320          // xemb row stride (ush)
#define WIHL 328          // Wih_r row stride
#define NH   512
#define WHHL 520          // Whh_r row stride
#define DH   1024
#define DHL  1032

static const size_t OFF_GX   = 0;              // gx     [256][128][2048] bf16 = 134,217,728
static const size_t OFF_XEMB = 134217728;      // xemb   [256][128][320] ush  = 20,971,520
static const size_t OFF_WIH  = 155189248;      // Wih_r  [2048][328] ush      = 1,343,488
static const size_t OFF_WHH  = 156532736;      // Whh_r  [2048][520] ush      = 2,129,920
static const size_t OFF_BWT  = 158662656;      // bWihT  [320][2048] ush      = 1,310,720
static const size_t OFF_DWHH = 159973376;      // dWhh_r [3072][1032] ush     = 6,340,608
static const size_t OFF_GI   = 166313984;      // gi     [6][3072] f32        = 73,728
static const size_t OFF_HR   = 166387712;      // h ring [2][128][512] ush    = 262,144
static const size_t OFF_FLAG = 166649856;      // flags  [256][8][32] u32     = 262,144
static const size_t OFF_BG   = 166912000;      // bgates [128][2048] f32      = 1,048,576
static const size_t OFF_HDEC = 167960576;      // h_dec  [2][128][1024] ush   = 524,288
// total = 168,484,864 (~161 MiB) -- requires ws_size >= this

// ---- embedding gather + tanh -> bf16 ---------------------------------------
__global__ __launch_bounds__(64) void embed_k(const int* __restrict__ seq,
                                              const float* __restrict__ embW,
                                              ush* __restrict__ xemb) {
    int t = blockIdx.x & 255, b = blockIdx.x >> 8;
    int tok = seq[b * NS + t];
    const float* src = embW + (size_t)tok * NE;
    ush* dst = xemb + ((size_t)t * NB + b) * XL;
    for (int e = threadIdx.x; e < XL; e += 64)
        dst[e] = (e < NE) ? f2b(tanhf(src[e])) : (ush)0;
}

// ---- weight conversions (natural row order, K padded) ----------------------
__global__ __launch_bounds__(128) void conv_wih(const float* __restrict__ W, ush* __restrict__ out) {
    int R = blockIdx.x;
    for (int k = threadIdx.x; k < WIHL; k += 128)
        out[(size_t)R * WIHL + k] = (k < NE) ? f2b(W[(size_t)R * NE + k]) : (ush)0;
}
__global__ __launch_bounds__(128) void conv_whh(const float* __restrict__ W, ush* __restrict__ out) {
    int R = blockIdx.x;
    for (int k = threadIdx.x; k < WHHL; k += 128)
        out[(size_t)R * WHHL + k] = (k < NH) ? f2b(W[(size_t)R * NH + k]) : (ush)0;
}
__global__ __launch_bounds__(256) void conv_bwihT(const float* __restrict__ W, ush* __restrict__ out) {
    int k = blockIdx.x;
    for (int r = threadIdx.x; r < 2048; r += 256)
        out[(size_t)k * 2048 + r] = (k < NE) ? f2b(W[(size_t)r * NE + k]) : (ush)0;
}
__global__ __launch_bounds__(128) void conv_dwhh(const float* __restrict__ W, ush* __restrict__ out) {
    int R = blockIdx.x;
    for (int k = threadIdx.x; k < DHL; k += 128)
        out[(size_t)R * DHL + k] = (k < DH) ? f2b(W[(size_t)R * DH + k]) : (ush)0;
}

// ---- gx GEMM: gx[t][b][col] = sum_k x[t][b][k] * Wih[col][k] ---------------
// grid (256 t, 2 mh), 256 thr. A tile 64x328 in LDS; B frags from L2.
__global__ __launch_bounds__(256) void gemm_gx(const ush* __restrict__ xemb,
                                               const ush* __restrict__ Wih_r,
                                               ush* __restrict__ gx) {
    __shared__ ush x_lds[64 * WIHL];           // 41,984 B
    const int t = blockIdx.x, mB = blockIdx.y * 64;
    const int tid = threadIdx.x, lane = tid & 63, v = tid >> 6;
    const int l15 = lane & 15, l4 = lane >> 4;
    const ush* src = xemb + ((size_t)t * NB + mB) * XL;
    for (int i = tid; i < 2560; i += 256) {    // 64 rows x 40 chunks of 8
        int r = i / 40, c = i - r * 40;
        *(us8*)&x_lds[r * WIHL + c * 8] = *(const us8*)&src[r * XL + c * 8];
    }
    __syncthreads();
    for (int nt = 0; nt < 32; ++nt) {
        const int col = v * 512 + nt * 16 + l15;
        bf16x8 bfr[10];
#pragma unroll
        for (int ks = 0; ks < 10; ++ks)
            bfr[ks] = ldf(&Wih_r[(size_t)col * WIHL + ks * 32 + l4 * 8]);
        f32x4 acc[4];
#pragma unroll
        for (int mt = 0; mt < 4; ++mt) {
            f32x4 a = {0.f, 0.f, 0.f, 0.f};
#pragma unroll
            for (int ks = 0; ks < 10; ++ks)
                a = mfma16(ldf(&x_lds[(mt * 16 + l15) * WIHL + ks * 32 + l4 * 8]), bfr[ks], a);
            acc[mt] = a;
        }
#pragma unroll
        for (int mt = 0; mt < 4; ++mt)
#pragma unroll
            for (int r0 = 0; r0 < 4; ++r0) {
                int m = mB + mt * 16 + l4 * 4 + r0;
                gx[((size_t)t * NB + m) * 2048 + col] = f2b(acc[mt][r0]);
            }
    }
}

// ---- decoder class-input projection ----------------------------------------
__global__ __launch_bounds__(256) void gi_k(const int* __restrict__ classes,
                                            const float* __restrict__ ecW,
                                            const float* __restrict__ dWih,
                                            const float* __restrict__ dbih,
                                            float* __restrict__ gi) {
    __shared__ float ce[NH];
    int c = blockIdx.x / 12, chunk = blockIdx.x % 12;
    int cls = classes[c];
    for (int i = threadIdx.x; i < NH; i += 256) ce[i] = tanhf(ecW[(size_t)cls * NH + i]);
    __syncthreads();
    int r = chunk * 256 + threadIdx.x;
    float acc = dbih[r];
    for (int k = 0; k < NH; ++k) acc += dWih[(size_t)r * NH + k] * ce[k];
    gi[c * 3072 + r] = acc;
}

// ---- backward-LSTM single step (h0 second half) ----------------------------
__global__ __launch_bounds__(256) void bgate_k(const ush* __restrict__ xemb,
                                               const ush* __restrict__ bWihT,
                                               const float* __restrict__ bb,
                                               float* __restrict__ bg) {
    int b = blockIdx.y, r = blockIdx.x * 256 + threadIdx.x;
    const ush* x0 = xemb + (size_t)b * XL;     // t=0 slab
    float acc = bb[r];
    for (int k = 0; k < NE; ++k) acc += b2f(x0[k]) * b2f(bWihT[(size_t)k * 2048 + r]);
    bg[(size_t)b * 2048 + r] = acc;
}
__global__ __launch_bounds__(256) void bpoint_k(const float* __restrict__ bg,
                                                ush* __restrict__ h_dec0) {
    int idx = blockIdx.x * 256 + threadIdx.x;
    int b = idx >> 9, j = idx & 511;
    const float* g = bg + (size_t)b * 2048;
    float c_ = sigm(g[j]) * tanhf(g[1024 + j]);
    float h_ = sigm(g[1536 + j]) * tanhf(c_);
    h_dec0[(size_t)b * DH + NH + j] = f2b(h_);
}

// ---- persistent LSTM scan (h-recurrence only) ------------------------------
// grid 64: group g = bid&7 (16 batch rows, XCD-local), WG w = bid>>3
// (dims w*64..+64). 16 waves: wave u = (gate v=u>>2, dsub d=u&3) computes a
// 16(batch)x16(gate-row) tile over K=512. gx streamed (prefetch t+1), Whh in
// VGPRs, group-h staged once/WG (16B/thread UC loads -> LDS).
__global__ __launch_bounds__(1024, 4) void lstm_scan(const ush* __restrict__ gx,
                                                     const ush* __restrict__ Whh_r,
                                                     const float* __restrict__ fb,
                                                     ush* __restrict__ h_ring,
                                                     ush* __restrict__ h_dec0,
                                                     unsigned* __restrict__ flags) {
    __shared__ ush h_stage[16 * WHHL];     // stride 520: 260 dw, %32=4 -> 2-way max
    __shared__ float gates[16 * 268];      // [batch][gate*64 + dim], 268: pad

    const int tid = threadIdx.x, lane = tid & 63;
    const int u = tid >> 6, v = u >> 2, d = u & 3;
    const int l15 = lane & 15, l4 = lane >> 4;
    const int g = (int)blockIdx.x & 7, w = (int)blockIdx.x >> 3;
    const int bl = tid >> 6, jd = tid & 63;    // gating: (batch row, dim-in-WG)
    const int dimG = w * 64 + jd;              // global h dim

    // Whh fragments -> VGPRs (16 frags = 64 VGPR), pinned
    bf16x8 hf[16];
    {
        const ush* hp = Whh_r + (size_t)(v * 512 + w * 64 + d * 16 + l15) * WHHL + l4 * 8;
#pragma unroll
        for (int ks = 0; ks < 16; ++ks) hf[ks] = ldf(hp + ks * 32);
    }
#pragma unroll
    for (int ks = 0; ks < 16; ++ks) {
        f32x4 tmp = __builtin_bit_cast(f32x4, hf[ks]);
        asm volatile("" : "+v"(tmp));
        hf[ks] = __builtin_bit_cast(bf16x8, tmp);
    }

    const float b0 = fb[dimG],        b1 = fb[512 + dimG],
                b2 = fb[1024 + dimG], b3 = fb[1536 + dimG];
    float c_reg = 0.f;

    // gx prefetch for t=0
    ush px0, px1, px2, px3;
    {
        const ush* gxr = gx + (size_t)(g * 16 + bl) * 2048 + dimG;
        px0 = gxr[0]; px1 = gxr[512]; px2 = gxr[1024]; px3 = gxr[1536];
    }

    for (int t = 0; t < NS; ++t) {
        f32x4 acc;
        if (t > 0) {
            // stage group-h (16KB) once: 16B per thread, UC loads -> LDS
            const u64* src = (const u64*)(h_ring + ((size_t)(t & 1) * NB + g * 16 + bl) * NH) + jd * 2;
            u64 e0 = __hip_atomic_load(src,     __ATOMIC_RELAXED, __HIP_MEMORY_SCOPE_AGENT);
            u64 e1 = __hip_atomic_load(src + 1, __ATOMIC_RELAXED, __HIP_MEMORY_SCOPE_AGENT);
            *(u64*)&h_stage[bl * WHHL + jd * 8]     = e0;
            *(u64*)&h_stage[bl * WHHL + jd * 8 + 4] = e1;
            __syncthreads();                               // sync_a
            f32x4 a0 = {0.f,0.f,0.f,0.f}, a1 = {0.f,0.f,0.f,0.f};
            const ush* hs = &h_stage[l15 * WHHL + l4 * 8];
#pragma unroll
            for (int ks = 0; ks < 16; ks += 2) {
                a0 = mfma16(ldf(hs + ks * 32),      hf[ks],     a0);
                a1 = mfma16(ldf(hs + ks * 32 + 32), hf[ks + 1], a1);
            }
            acc = a0 + a1;
        } else {
            acc = f32x4{0.f, 0.f, 0.f, 0.f};
        }
#pragma unroll
        for (int r0 = 0; r0 < 4; ++r0)
            gates[(l4 * 4 + r0) * 268 + v * 64 + d * 16 + l15] = acc[r0];
        __syncthreads();                                   // sync_b

        // gating: PyTorch gate order i,f,g,o
        float p0 = gates[bl * 268 + jd]       + b0 + b2f(px0);
        float p1 = gates[bl * 268 + 64 + jd]  + b1 + b2f(px1);
        float p2 = gates[bl * 268 + 128 + jd] + b2 + b2f(px2);
        float p3 = gates[bl * 268 + 192 + jd] + b3 + b2f(px3);
        float c_ = sigm(p1) * c_reg + sigm(p0) * tanhf(p2);
        float h_ = sigm(p3) * tanhf(c_);
        c_reg = c_;
        ush hb = f2b(h_);

        if (t == NS - 1) {
            h_dec0[(size_t)(g * 16 + bl) * DH + dimG] = hb;
            break;                                         // uniform
        }

        // publish h slice (pairs), no cache fences
        unsigned nbr = (unsigned)__shfl_down((int)hb, 1, 64);
        if ((jd & 1) == 0) {
            unsigned pair = (unsigned)hb | (nbr << 16);
            unsigned* dst = (unsigned*)&h_ring[((size_t)((t + 1) & 1) * NB + g * 16 + bl) * NH + dimG];
            __hip_atomic_store(dst, pair, __ATOMIC_RELAXED, __HIP_MEMORY_SCOPE_AGENT);
        }
        asm volatile("s_waitcnt vmcnt(0)" ::: "memory");   // h acked at MALL
        __syncthreads();                                   // sync_c
        if (tid == 0)
            __hip_atomic_store(&flags[((size_t)(t + 1) * 8 + g) * 32 + w], 1u,
                               __ATOMIC_RELAXED, __HIP_MEMORY_SCOPE_AGENT);

        // prefetch gx[t+1] (hidden under barrier)
        {
            const ush* gxr = gx + ((size_t)(t + 1) * NB + g * 16 + bl) * 2048 + dimG;
            px0 = gxr[0]; px1 = gxr[512]; px2 = gxr[1024]; px3 = gxr[1536];
        }

        // wait: 8 parallel flag loads per wave, fan-in 8
        {
            const unsigned* fl = flags + ((size_t)(t + 1) * 8 + g) * 32;
            bool done;
            do {
                unsigned f = (lane < 8)
                    ? __hip_atomic_load(fl + lane, __ATOMIC_RELAXED, __HIP_MEMORY_SCOPE_AGENT)
                    : 1u;
                done = __all(f != 0);
            } while (!done);
        }
    }
}

// ---- decoder GRU step ------------------------------------------------------
__global__ __launch_bounds__(256) void gru_step(const ush* __restrict__ h_in,
                                                ush* __restrict__ h_out,
                                                const ush* __restrict__ dWhh_r,
                                                const float* __restrict__ gi,
                                                const float* __restrict__ dbhh) {
    __shared__ ush h_lds[16 * DHL];
    const int tid = threadIdx.x, lane = tid & 63, v = tid >> 6;
    const int l15 = lane & 15, l4 = lane >> 4;
    const int bB = blockIdx.x * 16, jB = blockIdx.y * 64;

    for (int i = tid; i < 2048; i += 256) {
        int r = i >> 7, c = i & 127;
        *(us8*)&h_lds[r * DHL + c * 8] = *(const us8*)&h_in[(size_t)(bB + r) * DH + c * 8];
    }
    __syncthreads();

    const int jg = jB + v * 16 + l15;
    float b0 = dbhh[jg], b1 = dbhh[DH + jg], b2 = dbhh[2 * DH + jg];
    f32x4 aR = {b0, b0, b0, b0}, aZ = {b1, b1, b1, b1}, aN = {b2, b2, b2, b2};
    const ush* pR = dWhh_r + (size_t)(0 * DH + jg) * DHL + l4 * 8;
    const ush* pZ = dWhh_r + (size_t)(1 * DH + jg) * DHL + l4 * 8;
    const ush* pN = dWhh_r + (size_t)(2 * DH + jg) * DHL + l4 * 8;
#pragma unroll
    for (int ks = 0; ks < 32; ++ks) {
        bf16x8 a = ldf(&h_lds[l15 * DHL + ks * 32 + l4 * 8]);
        aR = mfma16(a, ldf(pR + ks * 32), aR);
        aZ = mfma16(a, ldf(pZ + ks * 32), aZ);
        aN = mfma16(a, ldf(pN + ks * 32), aN);
    }
    const float giR = gi[jg], giZ = gi[DH + jg], giN = gi[2 * DH + jg];
#pragma unroll
    for (int r0 = 0; r0 < 4; ++r0) {
        int m = l4 * 4 + r0;
        float r_ = sigm(giR + aR[r0]);
        float z_ = sigm(giZ + aZ[r0]);
        float n_ = tanhf(giN + r_ * aN[r0]);
        float hold = b2f(h_lds[m * DHL + jg]);
        float ho = tanhf((1.0f - z_) * n_ + z_ * hold);
        h_out[(size_t)(bB + m) * DH + jg] = f2b(ho);
    }
}

// ---- logits + log_softmax(2) ----------------------------------------------
__global__ __launch_bounds__(64) void logits_k(const ush* __restrict__ h,
                                               const float* __restrict__ clsW,
                                               const float* __restrict__ clsb,
                                               float* __restrict__ out) {
    int b = blockIdx.x, lane = threadIdx.x;
    float s0 = 0.f, s1 = 0.f;
    for (int k = lane; k < DH; k += 64) {
        float hv = b2f(h[(size_t)b * DH + k]);
        s0 += hv * clsW[k];
        s1 += hv * clsW[DH + k];
    }
    for (int off = 32; off; off >>= 1) {
        s0 += __shfl_down(s0, off, 64);
        s1 += __shfl_down(s1, off, 64);
    }
    if (lane == 0) {
        float l0 = s0 + clsb[0], l1 = s1 + clsb[1];
        float m = fmaxf(l0, l1);
        float dd = logf(expf(l0 - m) + expf(l1 - m));
        out[b * 2 + 0] = l0 - m - dd;
        out[b * 2 + 1] = l1 - m - dd;
    }
}

// ---------------------------------------------------------------------------
extern "C" void kernel_launch(void* const* d_in, const int* in_sizes, int n_in,
                              void* d_out, int out_size, void* d_ws, size_t ws_size,
                              hipStream_t stream) {
    (void)in_sizes; (void)n_in; (void)out_size; (void)ws_size;
    const int*   seq  = (const int*)  d_in[0];
    const int*   cls  = (const int*)  d_in[1];
    const float* embW = (const float*)d_in[2];
    const float* ecW  = (const float*)d_in[3];
    const float* fWih = (const float*)d_in[4];
    const float* fWhh = (const float*)d_in[5];
    const float* fb   = (const float*)d_in[6];
    const float* bWih = (const float*)d_in[7];
    /* d_in[8] = b_Whh unused (h0 = 0) */
    const float* bb   = (const float*)d_in[9];
    const float* dWih = (const float*)d_in[10];
    const float* dWhh = (const float*)d_in[11];
    const float* dbih = (const float*)d_in[12];
    const float* dbhh = (const float*)d_in[13];
    const float* clsW = (const float*)d_in[14];
    const float* clsb = (const float*)d_in[15];
    float* outF = (float*)d_out;

    char* ws = (char*)d_ws;
    ush*      gx      = (ush*)(ws + OFF_GX);
    ush*      xemb    = (ush*)(ws + OFF_XEMB);
    ush*      Wih_r   = (ush*)(ws + OFF_WIH);
    ush*      Whh_r   = (ush*)(ws + OFF_WHH);
    ush*      bWihT   = (ush*)(ws + OFF_BWT);
    ush*      dWhh_r  = (ush*)(ws + OFF_DWHH);
    float*    gi      = (float*)(ws + OFF_GI);
    ush*      h_ring  = (ush*)(ws + OFF_HR);
    unsigned* flags   = (unsigned*)(ws + OFF_FLAG);
    float*    bg      = (float*)(ws + OFF_BG);
    ush*      h_dec   = (ush*)(ws + OFF_HDEC);

    // zero barrier flags (graph replays this each run)
    hipMemsetAsync(ws + OFF_FLAG, 0, 262144, stream);

    embed_k<<<NB * NS, 64, 0, stream>>>(seq, embW, xemb);
    conv_wih<<<2048, 128, 0, stream>>>(fWih, Wih_r);
    conv_whh<<<2048, 128, 0, stream>>>(fWhh, Whh_r);
    conv_bwihT<<<320, 256, 0, stream>>>(bWih, bWihT);
    conv_dwhh<<<3072, 128, 0, stream>>>(dWhh, dWhh_r);
    gi_k<<<72, 256, 0, stream>>>(cls, ecW, dWih, dbih, gi);
    bgate_k<<<dim3(8, NB), 256, 0, stream>>>(xemb, bWihT, bb, bg);
    bpoint_k<<<256, 256, 0, stream>>>(bg, h_dec);

    gemm_gx<<<dim3(NS, 2), 256, 0, stream>>>(xemb, Wih_r, gx);

    lstm_scan<<<64, 1024, 0, stream>>>(gx, Whh_r, fb, h_ring, h_dec, flags);

    for (int c = 0; c < 6; ++c) {
        const ush* hin = h_dec + (size_t)(c & 1) * NB * DH;
        ush* hout      = h_dec + (size_t)((c + 1) & 1) * NB * DH;
        gru_step<<<dim3(8, 16), 256, 0, stream>>>(hin, hout, dWhh_r, gi + c * 3072, dbhh);
        logits_k<<<NB, 64, 0, stream>>>(hout, clsW, clsb, outF + c * NB * 2);
    }
}